// Round 16
// baseline (397.843 us; speedup 1.0000x reference)
//
#include <hip/hip_runtime.h>
#include <stdint.h>

#pragma clang fp contract(off)

#define NUM_CLASSES 81
#define TOP_K 200
#define BATCH 32
#define NUM_PRIORS 16384
#define CAP 512
#define CONF_T 0.01f
#define NMS_T 0.45f
#define PIVOT_S 0.97827148f
#define NTASK (BATCH * (NUM_CLASSES - 1))
#define QCAP 1536               // mean ~445 hits/block (256 rows), +50 sigma headroom
#define ROWS_PER_BLK 256
#define FILTER_BLOCKS 2048      // 64 chunks x 32 images
#define NB 1024                 // counting-sort buckets
#define NT 192                  // nms threads: 10 blocks/CU resident (single round)

typedef unsigned long long u64;
typedef unsigned int u32;

// Correctly-rounded f32 exp via f64 — verified bit-compatible R0-R14 (absmax 3e-8).
__device__ __forceinline__ float exp_ref(float x) {
#pragma clang fp contract(off)
    return (float)exp((double)x);
}

struct SharedBlk {
    union {
        u64 keys[CAP];              // phase 1-3: candidate keys
        float4 outstage4[250];      // phase 6: output slice staging (16B aligned)
    } k;
    union {
        u64 sup[TOP_K][4];          // phase 4+: suppression bitmasks (6400 B)
        struct { u32 bcnt[NB]; u32 flag; } srt;  // phase 2: counting sort
    } a;
    union {
        struct {
            float4 box4[TOP_K];     // x1,y1,x2,y2 (ds_read_b128); inf-padded >= nk
            float area[TOP_K];      // precomputed area (0 for padded rows)
            float score[TOP_K];
        } bx;                       // phase 3+ (4800 B)
        u64 keys2[CAP];             // phase 2: sorted output (4096 B)
    } b;
    u64 keep[4];
    u32 wsum[4];
    u32 acc;
    u32 ctr;
};

// Count elements with key > pivot (valid = score > CONF_T; invalid key == 0).
__device__ int count_pass(const float* cbase, u64 pivot, int tid, int lane, u32* s_acc) {
#pragma clang fp contract(off)
    __syncthreads();
    if (tid == 0) *s_acc = 0u;
    __syncthreads();
    u32 ph = (u32)(pivot >> 32), pl = (u32)pivot;
    u32 c = 0;
    for (int p = tid; p < NUM_PRIORS; p += NT) {
        float s = cbase[(size_t)p * NUM_CLASSES];
        bool valid = s > CONF_T;
        u32 bt = valid ? __float_as_uint(s) : 0u;
        u32 il = ~(u32)p;
        c += (valid && ((bt > ph) || ((bt == ph) && (il > pl)))) ? 1u : 0u;
    }
    for (int off = 32; off > 0; off >>= 1) c += __shfl_down(c, off, 64);
    if (lane == 0) atomicAdd(s_acc, c);
    __syncthreads();
    return (int)*s_acc;
}

// Count AND gather (capped at CAP) elements with key > pivot into s_keys.
__device__ int gather_pass(const float* cbase, u64 pivot, int tid, int lane,
                           u64* s_keys, u32* s_acc, u32* s_ctr) {
#pragma clang fp contract(off)
    __syncthreads();
    if (tid == 0) { *s_acc = 0u; *s_ctr = 0u; }
    for (int q = tid; q < CAP; q += NT) s_keys[q] = 0ull;
    __syncthreads();
    u32 ph = (u32)(pivot >> 32), pl = (u32)pivot;
    u32 cnt = 0;
    for (int p = tid; p < NUM_PRIORS; p += NT) {
        float s = cbase[(size_t)p * NUM_CLASSES];
        bool valid = s > CONF_T;
        u32 bt = valid ? __float_as_uint(s) : 0u;
        u32 il = ~(u32)p;
        bool pred = valid && ((bt > ph) || ((bt == ph) && (il > pl)));
        cnt += pred ? 1u : 0u;
        u64 mk = __ballot(pred);
        u32 off = 0;
        if (lane == 0 && mk) off = atomicAdd(s_ctr, (u32)__popcll(mk));
        off = __shfl(off, 0, 64);
        if (pred) {
            u32 pos = off + (u32)__popcll(mk & ((1ull << lane) - 1ull));
            if (pos < CAP) s_keys[pos] = ((u64)bt << 32) | il;
        }
    }
    for (int off2 = 32; off2 > 0; off2 >>= 1) cnt += __shfl_down(cnt, off2, 64);
    if (lane == 0) atomicAdd(s_acc, cnt);
    __syncthreads();
    return (int)*s_acc;
}

// Full bitonic sort of CAP u64 keys, descending (exact fallback path).
__device__ __forceinline__ void bitonic_desc(u64* k, int tid) {
    for (int k2 = 2; k2 <= CAP; k2 <<= 1) {
        for (int jj = k2 >> 1; jj > 0; jj >>= 1) {
            __syncthreads();
            for (int i = tid; i < CAP; i += NT) {
                int ixj = i ^ jj;
                if (ixj > i) {
                    u64 a = k[i], bb = k[ixj];
                    bool up = ((i & k2) == 0);
                    if (up ? (a < bb) : (a > bb)) { k[i] = bb; k[ixj] = a; }
                }
            }
        }
    }
    __syncthreads();
}

// ---- Kernel 1: coalesced filter (R8 structure — near stream floor). 256 thr.
__global__ __launch_bounds__(256) void filter_kernel(
    const float4* __restrict__ conf4,
    u32* __restrict__ counts, u64* __restrict__ keys)
{
#pragma clang fp contract(off)
    __shared__ u64 qkey[QCAP];
    __shared__ u32 tcnt[80];
    __shared__ u32 qn;

    const int tid = threadIdx.x;
    const int lane = tid & 63;
    const int bid = blockIdx.x;
    const int img = bid & 31;        // image pinned to one XCD (bid%8 fixed)
    const int chunk = bid >> 5;      // 64 chunks x 256 prior-rows
    const int row0 = img * NUM_PRIORS + chunk * ROWS_PER_BLK;
    const int base4 = row0 * NUM_CLASSES / 4;   // 256*81 = 20736 elems = 5184 float4

    if (tid == 0) qn = 0u;
    if (tid < 80) tcnt[tid] = 0u;
    __syncthreads();

    // 5184 float4 = 20*256 + 64
    #pragma unroll 4
    for (int it = 0; it < 21; ++it) {
        int le4 = tid + it * 256;
        if (it == 20 && tid >= 64) break;
        float4 v = conf4[base4 + le4];
        float vv[4] = {v.x, v.y, v.z, v.w};

        bool h0, h1, h2, h3;
        {
            u32 le0 = (u32)(le4 * 4);
            u32 r0 = le0 / NUM_CLASSES;            // magic-mul
            u32 c0 = le0 - r0 * NUM_CLASSES;
            h0 = (vv[0] > PIVOT_S) && (c0 != 0u);
            u32 c1 = c0 + 1u, c2 = c0 + 2u, c3 = c0 + 3u;
            h1 = (vv[1] > PIVOT_S) && (c1 != 81u);
            h2 = (vv[2] > PIVOT_S) && (c2 != 81u) && (c2 != 162u);
            h3 = (vv[3] > PIVOT_S) && (c3 != 81u) && (c3 != 162u);
        }
        u32 hc = (h0?1u:0u) + (h1?1u:0u) + (h2?1u:0u) + (h3?1u:0u);

        u64 b1 = __ballot(hc >= 1u);
        if (b1) {
            u64 b2 = __ballot(hc >= 2u);
            u64 b3 = __ballot(hc >= 3u);
            u64 b4 = __ballot(hc >= 4u);
            u32 tot = (u32)(__popcll(b1) + __popcll(b2) + __popcll(b3) + __popcll(b4));
            u32 base = 0;
            if (lane == 0) base = atomicAdd(&qn, tot);
            base = __shfl(base, 0, 64);
            if (hc) {
                u64 lt = (1ull << lane) - 1ull;
                u32 off = base + (u32)(__popcll(b1 & lt) + __popcll(b2 & lt)
                                     + __popcll(b3 & lt) + __popcll(b4 & lt));
                #pragma unroll
                for (int j = 0; j < 4; ++j) {
                    bool hj = (j == 0) ? h0 : (j == 1) ? h1 : (j == 2) ? h2 : h3;
                    if (hj) {
                        u32 le = (u32)(le4 * 4 + j);
                        u32 lrow = le / NUM_CLASSES;
                        u32 c = le - lrow * NUM_CLASSES;
                        u32 p = (u32)(chunk * ROWS_PER_BLK) + lrow;
                        u64 key = ((u64)__float_as_uint(vv[j]) << 32)
                                | ((u64)(16383u - p) << 7) | (u64)(c - 1u);
                        if (off < QCAP) qkey[off] = key;
                        ++off;
                    }
                }
            }
        }
    }
    __syncthreads();

    u32 qtotal = qn;
    u32 qvalid = qtotal < QCAP ? qtotal : QCAP;

    for (u32 q = tid; q < qvalid; q += 256)
        atomicAdd(&tcnt[(u32)(qkey[q] & 0x7Full)], 1u);
    __syncthreads();

    if (tid < 80) {
        u32 n = tcnt[tid];
        u32 base = 0;
        if (n) base = atomicAdd(&counts[img * 80 + tid], n);
        tcnt[tid] = base;
    }
    __syncthreads();

    for (u32 q = tid; q < qvalid; q += 256) {
        u64 k = qkey[q];
        u32 t = (u32)(k & 0x7Full);
        u32 slot = atomicAdd(&tcnt[t], 1u);
        if (slot < CAP) keys[(size_t)(img * 80 + t) * CAP + slot] = k;
    }
    if (qtotal > QCAP) {
        if (tid < 80) atomicAdd(&counts[img * 80 + tid], 0x01000000u);
    }
}

// Exact IoU-suppression test (R9 math, unchanged):
// fl32(inter/denom) > 0.45f  <=>  (double)inter > M45*(double)denom
// (M45 = (double)0.45f + 2^-26; 25b x 24b product exact; tie -> even = 0.45f).
__device__ __forceinline__ bool iou_sup(const float4& mybox, float aj,
                                        const float4& bk, float ak) {
#pragma clang fp contract(off)
    const double M45 = (double)0.45f + 0x1p-26;
    float ltx = fmaxf(mybox.x, bk.x);
    float lty = fmaxf(mybox.y, bk.y);
    float rbx = fminf(mybox.z, bk.z);
    float rby = fminf(mybox.w, bk.w);
    float wx = fmaxf(rbx - ltx, 0.0f);
    float wy = fmaxf(rby - lty, 0.0f);
    float inter = wx * wy;
    float uni = (aj + ak) - inter;
    float denom = fmaxf(uni, 1e-12f);
    return (double)inter > M45 * (double)denom;
}

// Full 64-wide chunk, descending k: 32-bit shift-accumulate (v_lshl_or_b32).
__device__ __forceinline__ u64 full_chunk64(const SharedBlk& sh, const float4& mybox,
                                            float aj, int k0) {
#pragma clang fp contract(off)
    u32 hi = 0u, lo = 0u;
    #pragma unroll 8
    for (int k = k0 + 63; k >= k0 + 32; --k)
        hi = (hi << 1) | (iou_sup(mybox, aj, sh.b.bx.box4[k], sh.b.bx.area[k]) ? 1u : 0u);
    #pragma unroll 8
    for (int k = k0 + 31; k >= k0; --k)
        lo = (lo << 1) | (iou_sup(mybox, aj, sh.b.bx.box4[k], sh.b.bx.area[k]) ? 1u : 0u);
    return (u64)lo | ((u64)hi << 32);
}

// Chunk 3 is only 8 wide (k = 192..199; box4 inf-padded above nk).
__device__ __forceinline__ u64 full_chunk8(const SharedBlk& sh, const float4& mybox,
                                           float aj) {
#pragma clang fp contract(off)
    u32 lo = 0u;
    #pragma unroll
    for (int k = 199; k >= 192; --k)
        lo = (lo << 1) | (iou_sup(mybox, aj, sh.b.bx.box4[k], sh.b.bx.area[k]) ? 1u : 0u);
    return (u64)lo;
}

// Row masks, specialized on the row's own chunk CJ (wave-uniform).
template<int CJ>
__device__ __forceinline__ void row_masks_t(const SharedBlk& sh, int j, u64 out[4]) {
#pragma clang fp contract(off)
    const float4 mybox = sh.b.bx.box4[j];
    const float aj = sh.b.bx.area[j];
    constexpr int OWN_END = ((CJ + 1) * 64 < TOP_K) ? (CJ + 1) * 64 : TOP_K;
    #pragma unroll
    for (int c = 0; c < CJ; ++c) out[c] = 0ull;
    // own chunk: variable start (R11-proven scattered pipelined form)
    {
        u64 mm = 0ull;
        for (int k = j + 1; k < OWN_END; ++k)
            if (iou_sup(mybox, aj, sh.b.bx.box4[k], sh.b.bx.area[k]))
                mm |= 1ull << (k & 63);
        out[CJ] = mm;
    }
    // later chunks: compile-time trip counts
    #pragma unroll
    for (int c = CJ + 1; c < 4; ++c) {
        if (c < 3) out[c] = full_chunk64(sh, mybox, aj, c * 64);
        else       out[c] = full_chunk8(sh, mybox, aj);
    }
}

// ---- Kernel 2: per-(img,class) counting-sort + NMS + fused output zeroing.
// 192 threads, min 8 waves/EU. Epilogue zeroes counts[task] for the next call
// (counts state affects speed path only, never output: garbage -> exact fallback).
__global__ __launch_bounds__(NT, 8) void nms_kernel(
    const float* __restrict__ loc_data,   // [B,P,4]
    const float* __restrict__ conf_data,  // [B*P,C]
    const float* __restrict__ prior_data, // [P,4]
    u32* __restrict__ counts,             // [NTASK] (may be null)
    const u64* __restrict__ gkeys,        // [NTASK][CAP] (may be null)
    float* __restrict__ out,              // [B,C,K,5] (NOT pre-zeroed; fully written here)
    int use_ws)
{
#pragma clang fp contract(off)
    __shared__ SharedBlk sh;
    const int tid = threadIdx.x;
    const int lane = tid & 63;
    const int wv = tid >> 6;              // 0..2
    const int b = blockIdx.x;
    const int img = b / 80;
    const int r = b - img * 80;
    const int cl = r + 1;
    const int task = img * 80 + r;
    // second row per thread: rows 192..199 handled by wave 2's last 8 lanes
    // (least-loaded wave; wave 0 lanes 0-7 own the longest rows 0-7).
    const int r2 = (tid >= NT - 8) ? tid + 8 : TOP_K;

    const float* cbase = conf_data + (size_t)img * NUM_PRIORS * NUM_CLASSES + cl;

    // ---- Phase 1: candidate set (ws fast path, else exact strided fallback)
    int m = -1;
    bool fast = false;
    if (use_ws) {
        u32 cnt = counts[task];
        if (cnt >= TOP_K && cnt <= CAP) {
            const u64* src = gkeys + (size_t)task * CAP;
            for (int q = tid; q < (int)cnt; q += NT) {
                u64 kw = src[q];
                u32 p = 16383u - ((u32)(kw >> 7) & 0x3FFFu);
                sh.k.keys[q] = (kw & 0xFFFFFFFF00000000ull) | (u64)(u32)(~p);
            }
            m = (int)cnt;
            fast = true;
        }
    }
    if (m < 0) {
        u64 pivot = ((u64)__float_as_uint(PIVOT_S) << 32) | 0xFFFFFFFFull;
        m = gather_pass(cbase, pivot, tid, lane, sh.k.keys, &sh.acc, &sh.ctr);
        if (m < TOP_K || m > CAP) {
            const u32 B001 = __float_as_uint(CONF_T);
            int nvalid = count_pass(cbase, ((u64)B001 << 32) | 0xFFFFFFFFull, tid, lane, &sh.acc);
            if (nvalid <= CAP) {
                pivot = 0ull;  // gather all valid
            } else {
                u64 lo = ((u64)B001 << 32) | 0xFFFFFFFFull;
                u64 hi = ~0ull;
                for (int it = 0; it < 64; ++it) {
                    u64 mid = lo + ((hi - lo) >> 1);
                    int c = count_pass(cbase, mid, tid, lane, &sh.acc);
                    if (c >= TOP_K && c <= CAP) { pivot = mid; break; }
                    if (c > CAP) lo = mid; else hi = mid;
                }
            }
            m = gather_pass(cbase, pivot, tid, lane, sh.k.keys, &sh.acc, &sh.ctr);
        }
    }
    const int nk = m < TOP_K ? m : TOP_K;

    // ---- Phase 2: sort m keys descending (counting sort fast path).
    bool in_k2 = false;
    if (fast) {
        for (int i = tid; i < NB; i += NT) sh.a.srt.bcnt[i] = 0u;
        if (tid == 0) sh.a.srt.flag = 0u;
        __syncthreads();
        const u32 LOB = __float_as_uint(PIVOT_S);
        for (int q = tid; q < m; q += NT) {
            u32 sb = (u32)(sh.k.keys[q] >> 32);
            u32 bi = (sb - LOB - 1u) >> 9;
            if (bi > (u32)(NB - 1)) bi = (u32)(NB - 1);
            atomicAdd(&sh.a.srt.bcnt[(u32)(NB - 1) - bi], 1u);   // bucket asc = score desc
        }
        __syncthreads();
        // exclusive scan over NB bins: 6 bins/thread (192*6=1152 >= 1024)
        u32 c[6];
        u32 s = 0;
        const int bb0 = tid * 6;
        #pragma unroll
        for (int i = 0; i < 6; ++i) {
            int idx = bb0 + i;
            c[i] = (idx < NB) ? sh.a.srt.bcnt[idx] : 0u;
            s += c[i];
        }
        u32 inc = s;
        #pragma unroll
        for (int o = 1; o < 64; o <<= 1) {
            u32 t = __shfl_up(inc, o, 64);
            if (lane >= o) inc += t;
        }
        if (lane == 63) sh.wsum[wv] = inc;
        __syncthreads();
        u32 wpre = 0;
        #pragma unroll
        for (int w = 0; w < 3; ++w) wpre += (w < wv) ? sh.wsum[w] : 0u;
        u32 run = wpre + inc - s;
        #pragma unroll
        for (int i = 0; i < 6; ++i) {
            int idx = bb0 + i;
            if (idx < NB) sh.a.srt.bcnt[idx] = run;
            run += c[i];
        }
        __syncthreads();
        // scatter (bins become end-cursors)
        for (int q = tid; q < m; q += NT) {
            u64 k = sh.k.keys[q];
            u32 sb = (u32)(k >> 32);
            u32 bi = (sb - LOB - 1u) >> 9;
            if (bi > (u32)(NB - 1)) bi = (u32)(NB - 1);
            u32 slot = atomicAdd(&sh.a.srt.bcnt[(u32)(NB - 1) - bi], 1u);
            sh.b.keys2[slot] = k;
        }
        __syncthreads();
        // per-bucket insertion sort desc (full 64-bit keys -> deterministic)
        for (int bb = tid; bb < NB; bb += NT) {
            u32 e = sh.a.srt.bcnt[bb];
            u32 st = bb ? sh.a.srt.bcnt[bb - 1] : 0u;
            if ((int)(e - st) > 32) { sh.a.srt.flag = 1u; continue; }
            for (u32 i = st + 1; i < e; ++i) {
                u64 x = sh.b.keys2[i];
                int j = (int)i - 1;
                while (j >= (int)st && sh.b.keys2[j] < x) {
                    sh.b.keys2[j + 1] = sh.b.keys2[j];
                    --j;
                }
                sh.b.keys2[j + 1] = x;
            }
        }
        __syncthreads();
        u32 fl = sh.a.srt.flag;
        if (!fl) {
            in_k2 = true;
        } else {
            // ~impossible exact fallback: zero-fill tail then full bitonic
            for (int q = tid; q < CAP; q += NT)
                if (q >= m) sh.k.keys[q] = 0ull;
            bitonic_desc(sh.k.keys, tid);
        }
    } else {
        bitonic_desc(sh.k.keys, tid);
    }

    // ---- Phase 3: decode candidate boxes (reference op order). Rows tid and
    // r2; BOTH keys read before the sync that allows box4 (union with keys2)
    // to be overwritten. Rows in [nk, TOP_K) are inf-padded (inter=0 -> never
    // suppress) so phase 4 can run fixed-trip chunk loops.
    {
        u64 k1 = 0ull, k2 = 0ull;
        if (tid < nk) k1 = in_k2 ? sh.b.keys2[tid] : sh.k.keys[tid];
        if (r2 < nk)  k2 = in_k2 ? sh.b.keys2[r2]  : sh.k.keys[r2];
        float4 lc1, pr1, lc2, pr2;
        if (tid < nk) {
            int p = (int)(~(u32)k1);
            lc1 = *(const float4*)(loc_data + ((size_t)img * NUM_PRIORS + p) * 4);
            pr1 = *(const float4*)(prior_data + (size_t)p * 4);
        }
        if (r2 < nk) {
            int p = (int)(~(u32)k2);
            lc2 = *(const float4*)(loc_data + ((size_t)img * NUM_PRIORS + p) * 4);
            pr2 = *(const float4*)(prior_data + (size_t)p * 4);
        }
        __syncthreads();   // keys2 fully consumed before box4 overwrites it
        const float INF = __int_as_float(0x7f800000);
        if (tid < TOP_K) {
            if (tid < nk) {
                float sc = __uint_as_float((u32)(k1 >> 32));
                float cx = pr1.x + (lc1.x * 0.1f) * pr1.z;
                float cy = pr1.y + (lc1.y * 0.1f) * pr1.w;
                float w  = pr1.z * exp_ref(lc1.z * 0.2f);
                float h  = pr1.w * exp_ref(lc1.w * 0.2f);
                float x1 = cx - 0.5f * w;
                float y1 = cy - 0.5f * h;
                float x2 = x1 + w;
                float y2 = y1 + h;
                sh.b.bx.box4[tid] = make_float4(x1, y1, x2, y2);
                sh.b.bx.area[tid] = fmaxf(x2 - x1, 0.0f) * fmaxf(y2 - y1, 0.0f);
                sh.b.bx.score[tid] = sc;
            } else {
                sh.b.bx.box4[tid] = make_float4(INF, INF, INF, INF);
                sh.b.bx.area[tid] = 0.0f;
                sh.b.bx.score[tid] = 0.0f;
            }
        }
        if (r2 < TOP_K) {
            if (r2 < nk) {
                float sc = __uint_as_float((u32)(k2 >> 32));
                float cx = pr2.x + (lc2.x * 0.1f) * pr2.z;
                float cy = pr2.y + (lc2.y * 0.1f) * pr2.w;
                float w  = pr2.z * exp_ref(lc2.z * 0.2f);
                float h  = pr2.w * exp_ref(lc2.w * 0.2f);
                float x1 = cx - 0.5f * w;
                float y1 = cy - 0.5f * h;
                float x2 = x1 + w;
                float y2 = y1 + h;
                sh.b.bx.box4[r2] = make_float4(x1, y1, x2, y2);
                sh.b.bx.area[r2] = fmaxf(x2 - x1, 0.0f) * fmaxf(y2 - y1, 0.0f);
                sh.b.bx.score[r2] = sc;
            } else {
                sh.b.bx.box4[r2] = make_float4(INF, INF, INF, INF);
                sh.b.bx.area[r2] = 0.0f;
                sh.b.bx.score[r2] = 0.0f;
            }
        }
    }
    __syncthreads();

    // ---- Phase 4: row-per-thread suppression masks (rows tid and r2),
    // chunk-specialized (CJ = wv is wave-uniform; r2 rows always chunk 3).
    {
        u64 mm1[4] = {0ull, 0ull, 0ull, 0ull};
        u64 mm2[4] = {0ull, 0ull, 0ull, 0ull};
        if (tid < nk) {
            if (wv == 0)      row_masks_t<0>(sh, tid, mm1);
            else if (wv == 1) row_masks_t<1>(sh, tid, mm1);
            else              row_masks_t<2>(sh, tid, mm1);
        }
        if (r2 < nk) row_masks_t<3>(sh, r2, mm2);
        if (tid < TOP_K) {
            sh.a.sup[tid][0] = mm1[0]; sh.a.sup[tid][1] = mm1[1];
            sh.a.sup[tid][2] = mm1[2]; sh.a.sup[tid][3] = mm1[3];
        }
        if (r2 < TOP_K) {
            sh.a.sup[r2][0] = mm2[0]; sh.a.sup[r2][1] = mm2[1];
            sh.a.sup[r2][2] = mm2[2]; sh.a.sup[r2][3] = mm2[3];
        }
    }
    __syncthreads();

    // ---- Phase 5: greedy resolve on wave 0 (64-bit chunks, shfl broadcast)
    if (wv == 0) {
        u64 kws[4];
        #pragma unroll
        for (int w = 0; w < 4; ++w) {
            int rem = nk - (w << 6);
            kws[w] = rem >= 64 ? ~0ull : (rem <= 0 ? 0ull : ((1ull << rem) - 1ull));
        }
        for (int c = 0; c < 4; ++c) {
            int row = (c << 6) + lane;
            u64 myrow = (row < TOP_K) ? sh.a.sup[row][c] : 0ull;
            u64 kw = kws[c];
            u64 nz = __ballot(myrow != 0ull);
            u64 t = kw & nz;
            while (t) {
                int j = __ffsll(t) - 1;
                u64 rj = __shfl(myrow, j, 64);
                kw &= ~rj;
                t &= ~(1ull << j);
                t &= kw;
            }
            kws[c] = kw;
            for (int w2 = c + 1; w2 < 4; ++w2) {
                u64 contrib = (row < TOP_K && ((kw >> lane) & 1ull)) ? sh.a.sup[row][w2] : 0ull;
                #pragma unroll
                for (int off = 32; off > 0; off >>= 1) contrib |= __shfl_xor(contrib, off, 64);
                kws[w2] &= ~contrib;
            }
        }
        if (lane == 0) {
            sh.keep[0] = kws[0]; sh.keep[1] = kws[1];
            sh.keep[2] = kws[2]; sh.keep[3] = kws[3];
        }
    }
    __syncthreads();

    // ---- Phase 6: stable compaction into LDS staging, then coalesced store.
    {
        float* os = (float*)sh.k.outstage4;
        for (int i = tid; i < (TOP_K * 5) / 2; i += NT) ((u64*)os)[i] = 0ull;
        __syncthreads();
        for (int row = tid; row < nk; row += NT) {
            int w = row >> 6, rr = row & 63;
            u64 kwv = sh.keep[w];
            if ((kwv >> rr) & 1ull) {
                int pos = __popcll(kwv & ((1ull << rr) - 1ull));
                for (int q = 0; q < w; ++q) pos += __popcll(sh.keep[q]);
                float4 bx = sh.b.bx.box4[row];
                os[pos * 5 + 0] = sh.b.bx.score[row];
                os[pos * 5 + 1] = bx.x;
                os[pos * 5 + 2] = bx.y;
                os[pos * 5 + 3] = bx.z;
                os[pos * 5 + 4] = bx.w;
            }
        }
        __syncthreads();
        float4* oslice = (float4*)(out + (((size_t)img * NUM_CLASSES + cl) * TOP_K) * 5);
        for (int i = tid; i < 250; i += NT) oslice[i] = sh.k.outstage4[i];
        if (r == 0) {  // this block also zeroes its image's class-0 (background) slice
            float4* bg = (float4*)(out + (((size_t)img * NUM_CLASSES) * TOP_K) * 5);
            for (int i = tid; i < 250; i += NT) bg[i] = make_float4(0.f, 0.f, 0.f, 0.f);
        }
    }

    // ---- Epilogue: zero this task's counter for the next call (replaces the
    // host-side memset dispatch). Counts state only selects fast vs exact
    // fallback path; output is bit-identical either way.
    if (use_ws && tid == 0) counts[task] = 0u;
}

extern "C" void kernel_launch(void* const* d_in, const int* in_sizes, int n_in,
                              void* d_out, int out_size, void* d_ws, size_t ws_size,
                              hipStream_t stream) {
    const float* loc   = (const float*)d_in[0];
    const float* conf  = (const float*)d_in[1];
    const float* prior = (const float*)d_in[2];
    float* out = (float*)d_out;

    // ws layout: [0, NTASK*4) counts | [65536, 65536 + NTASK*CAP*8) keys
    const size_t need = 65536 + (size_t)NTASK * CAP * 8;
    const int use_ws = (ws_size >= need) ? 1 : 0;   // constant per session -> deterministic

    u32* counts = (u32*)d_ws;
    u64* keys   = (u64*)((char*)d_ws + 65536);

    if (use_ws) {
        filter_kernel<<<FILTER_BLOCKS, 256, 0, stream>>>((const float4*)conf, counts, keys);
    }
    nms_kernel<<<NTASK, NT, 0, stream>>>(loc, conf, prior,
                                         use_ws ? counts : nullptr,
                                         use_ws ? keys : nullptr,
                                         out, use_ws);
}

// Round 17
// 106.344 us; speedup vs baseline: 3.7411x; 3.7411x over previous
//
#include <hip/hip_runtime.h>
#include <stdint.h>

#pragma clang fp contract(off)

#define NUM_CLASSES 81
#define TOP_K 200
#define BATCH 32
#define NUM_PRIORS 16384
#define CAP 512
#define CONF_T 0.01f
#define NMS_T 0.45f
#define PIVOT_S 0.97827148f
#define NTASK (BATCH * (NUM_CLASSES - 1))
#define QCAP 1536               // mean ~445 hits/block (256 rows), +50 sigma headroom
#define ROWS_PER_BLK 256
#define FILTER_BLOCKS 2048      // 64 chunks x 32 images
#define NB 1024                 // counting-sort buckets
#define NT 192                  // nms threads: 10 blocks/CU resident (single round)

typedef unsigned long long u64;
typedef unsigned int u32;

// Correctly-rounded f32 exp via f64 — verified bit-compatible R0-R15 (absmax 3e-8).
__device__ __forceinline__ float exp_ref(float x) {
#pragma clang fp contract(off)
    return (float)exp((double)x);
}

struct SharedBlk {
    union {
        u64 keys[CAP];              // phase 1-3: candidate keys
        float4 outstage4[250];      // phase 6: output slice staging (16B aligned)
    } k;
    union {
        u64 sup[TOP_K][4];          // phase 4+: suppression bitmasks (6400 B)
        struct { u32 bcnt[NB]; u32 flag; } srt;  // phase 2: counting sort
    } a;
    union {
        struct {
            float4 box4[TOP_K];     // x1,y1,x2,y2 (ds_read_b128); inf-padded >= nk
            float area[TOP_K];      // precomputed area (0 for padded rows)
            float score[TOP_K];
        } bx;                       // phase 3+ (4800 B)
        u64 keys2[CAP];             // phase 2: sorted output (4096 B)
    } b;
    u64 keep[4];
    u32 wsum[4];
    u32 acc;
    u32 ctr;
};

// Count elements with key > pivot (valid = score > CONF_T; invalid key == 0).
__device__ int count_pass(const float* cbase, u64 pivot, int tid, int lane, u32* s_acc) {
#pragma clang fp contract(off)
    __syncthreads();
    if (tid == 0) *s_acc = 0u;
    __syncthreads();
    u32 ph = (u32)(pivot >> 32), pl = (u32)pivot;
    u32 c = 0;
    for (int p = tid; p < NUM_PRIORS; p += NT) {
        float s = cbase[(size_t)p * NUM_CLASSES];
        bool valid = s > CONF_T;
        u32 bt = valid ? __float_as_uint(s) : 0u;
        u32 il = ~(u32)p;
        c += (valid && ((bt > ph) || ((bt == ph) && (il > pl)))) ? 1u : 0u;
    }
    for (int off = 32; off > 0; off >>= 1) c += __shfl_down(c, off, 64);
    if (lane == 0) atomicAdd(s_acc, c);
    __syncthreads();
    return (int)*s_acc;
}

// Count AND gather (capped at CAP) elements with key > pivot into s_keys.
__device__ int gather_pass(const float* cbase, u64 pivot, int tid, int lane,
                           u64* s_keys, u32* s_acc, u32* s_ctr) {
#pragma clang fp contract(off)
    __syncthreads();
    if (tid == 0) { *s_acc = 0u; *s_ctr = 0u; }
    for (int q = tid; q < CAP; q += NT) s_keys[q] = 0ull;
    __syncthreads();
    u32 ph = (u32)(pivot >> 32), pl = (u32)pivot;
    u32 cnt = 0;
    for (int p = tid; p < NUM_PRIORS; p += NT) {
        float s = cbase[(size_t)p * NUM_CLASSES];
        bool valid = s > CONF_T;
        u32 bt = valid ? __float_as_uint(s) : 0u;
        u32 il = ~(u32)p;
        bool pred = valid && ((bt > ph) || ((bt == ph) && (il > pl)));
        cnt += pred ? 1u : 0u;
        u64 mk = __ballot(pred);
        u32 off = 0;
        if (lane == 0 && mk) off = atomicAdd(s_ctr, (u32)__popcll(mk));
        off = __shfl(off, 0, 64);
        if (pred) {
            u32 pos = off + (u32)__popcll(mk & ((1ull << lane) - 1ull));
            if (pos < CAP) s_keys[pos] = ((u64)bt << 32) | il;
        }
    }
    for (int off2 = 32; off2 > 0; off2 >>= 1) cnt += __shfl_down(cnt, off2, 64);
    if (lane == 0) atomicAdd(s_acc, cnt);
    __syncthreads();
    return (int)*s_acc;
}

// Full bitonic sort of CAP u64 keys, descending (exact fallback path).
__device__ __forceinline__ void bitonic_desc(u64* k, int tid) {
    for (int k2 = 2; k2 <= CAP; k2 <<= 1) {
        for (int jj = k2 >> 1; jj > 0; jj >>= 1) {
            __syncthreads();
            for (int i = tid; i < CAP; i += NT) {
                int ixj = i ^ jj;
                if (ixj > i) {
                    u64 a = k[i], bb = k[ixj];
                    bool up = ((i & k2) == 0);
                    if (up ? (a < bb) : (a > bb)) { k[i] = bb; k[ixj] = a; }
                }
            }
        }
    }
    __syncthreads();
}

// ---- Kernel 1: coalesced filter (R8 structure — near stream floor). 256 thr.
__global__ __launch_bounds__(256) void filter_kernel(
    const float4* __restrict__ conf4,
    u32* __restrict__ counts, u64* __restrict__ keys)
{
#pragma clang fp contract(off)
    __shared__ u64 qkey[QCAP];
    __shared__ u32 tcnt[80];
    __shared__ u32 qn;

    const int tid = threadIdx.x;
    const int lane = tid & 63;
    const int bid = blockIdx.x;
    const int img = bid & 31;        // image pinned to one XCD (bid%8 fixed)
    const int chunk = bid >> 5;      // 64 chunks x 256 prior-rows
    const int row0 = img * NUM_PRIORS + chunk * ROWS_PER_BLK;
    const int base4 = row0 * NUM_CLASSES / 4;   // 256*81 = 20736 elems = 5184 float4

    if (tid == 0) qn = 0u;
    if (tid < 80) tcnt[tid] = 0u;
    __syncthreads();

    // 5184 float4 = 20*256 + 64
    #pragma unroll 4
    for (int it = 0; it < 21; ++it) {
        int le4 = tid + it * 256;
        if (it == 20 && tid >= 64) break;
        float4 v = conf4[base4 + le4];
        float vv[4] = {v.x, v.y, v.z, v.w};

        bool h0, h1, h2, h3;
        {
            u32 le0 = (u32)(le4 * 4);
            u32 r0 = le0 / NUM_CLASSES;            // magic-mul
            u32 c0 = le0 - r0 * NUM_CLASSES;
            h0 = (vv[0] > PIVOT_S) && (c0 != 0u);
            u32 c1 = c0 + 1u, c2 = c0 + 2u, c3 = c0 + 3u;
            h1 = (vv[1] > PIVOT_S) && (c1 != 81u);
            h2 = (vv[2] > PIVOT_S) && (c2 != 81u) && (c2 != 162u);
            h3 = (vv[3] > PIVOT_S) && (c3 != 81u) && (c3 != 162u);
        }
        u32 hc = (h0?1u:0u) + (h1?1u:0u) + (h2?1u:0u) + (h3?1u:0u);

        u64 b1 = __ballot(hc >= 1u);
        if (b1) {
            u64 b2 = __ballot(hc >= 2u);
            u64 b3 = __ballot(hc >= 3u);
            u64 b4 = __ballot(hc >= 4u);
            u32 tot = (u32)(__popcll(b1) + __popcll(b2) + __popcll(b3) + __popcll(b4));
            u32 base = 0;
            if (lane == 0) base = atomicAdd(&qn, tot);
            base = __shfl(base, 0, 64);
            if (hc) {
                u64 lt = (1ull << lane) - 1ull;
                u32 off = base + (u32)(__popcll(b1 & lt) + __popcll(b2 & lt)
                                     + __popcll(b3 & lt) + __popcll(b4 & lt));
                #pragma unroll
                for (int j = 0; j < 4; ++j) {
                    bool hj = (j == 0) ? h0 : (j == 1) ? h1 : (j == 2) ? h2 : h3;
                    if (hj) {
                        u32 le = (u32)(le4 * 4 + j);
                        u32 lrow = le / NUM_CLASSES;
                        u32 c = le - lrow * NUM_CLASSES;
                        u32 p = (u32)(chunk * ROWS_PER_BLK) + lrow;
                        u64 key = ((u64)__float_as_uint(vv[j]) << 32)
                                | ((u64)(16383u - p) << 7) | (u64)(c - 1u);
                        if (off < QCAP) qkey[off] = key;
                        ++off;
                    }
                }
            }
        }
    }
    __syncthreads();

    u32 qtotal = qn;
    u32 qvalid = qtotal < QCAP ? qtotal : QCAP;

    for (u32 q = tid; q < qvalid; q += 256)
        atomicAdd(&tcnt[(u32)(qkey[q] & 0x7Full)], 1u);
    __syncthreads();

    if (tid < 80) {
        u32 n = tcnt[tid];
        u32 base = 0;
        if (n) base = atomicAdd(&counts[img * 80 + tid], n);
        tcnt[tid] = base;
    }
    __syncthreads();

    for (u32 q = tid; q < qvalid; q += 256) {
        u64 k = qkey[q];
        u32 t = (u32)(k & 0x7Full);
        u32 slot = atomicAdd(&tcnt[t], 1u);
        if (slot < CAP) keys[(size_t)(img * 80 + t) * CAP + slot] = k;
    }
    if (qtotal > QCAP) {
        if (tid < 80) atomicAdd(&counts[img * 80 + tid], 0x01000000u);
    }
}

// Exact IoU-suppression test (R9 math, unchanged):
// fl32(inter/denom) > 0.45f  <=>  (double)inter > M45*(double)denom
// (M45 = (double)0.45f + 2^-26; 25b x 24b product exact; tie -> even = 0.45f).
__device__ __forceinline__ bool iou_sup(const float4& mybox, float aj,
                                        const float4& bk, float ak) {
#pragma clang fp contract(off)
    const double M45 = (double)0.45f + 0x1p-26;
    float ltx = fmaxf(mybox.x, bk.x);
    float lty = fmaxf(mybox.y, bk.y);
    float rbx = fminf(mybox.z, bk.z);
    float rby = fminf(mybox.w, bk.w);
    float wx = fmaxf(rbx - ltx, 0.0f);
    float wy = fmaxf(rby - lty, 0.0f);
    float inter = wx * wy;
    float uni = (aj + ak) - inter;
    float denom = fmaxf(uni, 1e-12f);
    return (double)inter > M45 * (double)denom;
}

// Full 64-wide chunk, descending k: 32-bit shift-accumulate (v_lshl_or_b32).
__device__ __forceinline__ u64 full_chunk64(const SharedBlk& sh, const float4& mybox,
                                            float aj, int k0) {
#pragma clang fp contract(off)
    u32 hi = 0u, lo = 0u;
    #pragma unroll 8
    for (int k = k0 + 63; k >= k0 + 32; --k)
        hi = (hi << 1) | (iou_sup(mybox, aj, sh.b.bx.box4[k], sh.b.bx.area[k]) ? 1u : 0u);
    #pragma unroll 8
    for (int k = k0 + 31; k >= k0; --k)
        lo = (lo << 1) | (iou_sup(mybox, aj, sh.b.bx.box4[k], sh.b.bx.area[k]) ? 1u : 0u);
    return (u64)lo | ((u64)hi << 32);
}

// Chunk 3 is only 8 wide (k = 192..199; box4 inf-padded above nk).
__device__ __forceinline__ u64 full_chunk8(const SharedBlk& sh, const float4& mybox,
                                           float aj) {
#pragma clang fp contract(off)
    u32 lo = 0u;
    #pragma unroll
    for (int k = 199; k >= 192; --k)
        lo = (lo << 1) | (iou_sup(mybox, aj, sh.b.bx.box4[k], sh.b.bx.area[k]) ? 1u : 0u);
    return (u64)lo;
}

// Row masks, specialized on the row's own chunk CJ (wave-uniform).
template<int CJ>
__device__ __forceinline__ void row_masks_t(const SharedBlk& sh, int j, u64 out[4]) {
#pragma clang fp contract(off)
    const float4 mybox = sh.b.bx.box4[j];
    const float aj = sh.b.bx.area[j];
    constexpr int OWN_END = ((CJ + 1) * 64 < TOP_K) ? (CJ + 1) * 64 : TOP_K;
    #pragma unroll
    for (int c = 0; c < CJ; ++c) out[c] = 0ull;
    // own chunk: variable start (R11-proven scattered pipelined form)
    {
        u64 mm = 0ull;
        for (int k = j + 1; k < OWN_END; ++k)
            if (iou_sup(mybox, aj, sh.b.bx.box4[k], sh.b.bx.area[k]))
                mm |= 1ull << (k & 63);
        out[CJ] = mm;
    }
    // later chunks: compile-time trip counts
    #pragma unroll
    for (int c = CJ + 1; c < 4; ++c) {
        if (c < 3) out[c] = full_chunk64(sh, mybox, aj, c * 64);
        else       out[c] = full_chunk8(sh, mybox, aj);
    }
}

// ---- Kernel 2: per-(img,class) counting-sort + NMS + fused output zeroing.
// 192 threads, min 8 waves/EU: VGPR capped at 64 -> 10 blocks/CU co-resident.
__global__ __launch_bounds__(NT, 8) void nms_kernel(
    const float* __restrict__ loc_data,   // [B,P,4]
    const float* __restrict__ conf_data,  // [B*P,C]
    const float* __restrict__ prior_data, // [P,4]
    const u32* __restrict__ counts,       // [NTASK] (may be null)
    const u64* __restrict__ gkeys,        // [NTASK][CAP] (may be null)
    float* __restrict__ out,              // [B,C,K,5] (NOT pre-zeroed; fully written here)
    int use_ws)
{
#pragma clang fp contract(off)
    __shared__ SharedBlk sh;
    const int tid = threadIdx.x;
    const int lane = tid & 63;
    const int wv = tid >> 6;              // 0..2
    const int b = blockIdx.x;
    const int img = b / 80;
    const int r = b - img * 80;
    const int cl = r + 1;
    const int task = img * 80 + r;
    // second row per thread: rows 192..199 handled by wave 2's last 8 lanes
    // (least-loaded wave; wave 0 lanes 0-7 own the longest rows 0-7).
    const int r2 = (tid >= NT - 8) ? tid + 8 : TOP_K;

    const float* cbase = conf_data + (size_t)img * NUM_PRIORS * NUM_CLASSES + cl;

    // ---- Phase 1: candidate set (ws fast path, else exact strided fallback)
    int m = -1;
    bool fast = false;
    if (use_ws) {
        u32 cnt = counts[task];
        if (cnt >= TOP_K && cnt <= CAP) {
            const u64* src = gkeys + (size_t)task * CAP;
            for (int q = tid; q < (int)cnt; q += NT) {
                u64 kw = src[q];
                u32 p = 16383u - ((u32)(kw >> 7) & 0x3FFFu);
                sh.k.keys[q] = (kw & 0xFFFFFFFF00000000ull) | (u64)(u32)(~p);
            }
            m = (int)cnt;
            fast = true;
        }
    }
    if (m < 0) {
        u64 pivot = ((u64)__float_as_uint(PIVOT_S) << 32) | 0xFFFFFFFFull;
        m = gather_pass(cbase, pivot, tid, lane, sh.k.keys, &sh.acc, &sh.ctr);
        if (m < TOP_K || m > CAP) {
            const u32 B001 = __float_as_uint(CONF_T);
            int nvalid = count_pass(cbase, ((u64)B001 << 32) | 0xFFFFFFFFull, tid, lane, &sh.acc);
            if (nvalid <= CAP) {
                pivot = 0ull;  // gather all valid
            } else {
                u64 lo = ((u64)B001 << 32) | 0xFFFFFFFFull;
                u64 hi = ~0ull;
                for (int it = 0; it < 64; ++it) {
                    u64 mid = lo + ((hi - lo) >> 1);
                    int c = count_pass(cbase, mid, tid, lane, &sh.acc);
                    if (c >= TOP_K && c <= CAP) { pivot = mid; break; }
                    if (c > CAP) lo = mid; else hi = mid;
                }
            }
            m = gather_pass(cbase, pivot, tid, lane, sh.k.keys, &sh.acc, &sh.ctr);
        }
    }
    const int nk = m < TOP_K ? m : TOP_K;

    // ---- Phase 2: sort m keys descending (counting sort fast path).
    bool in_k2 = false;
    if (fast) {
        for (int i = tid; i < NB; i += NT) sh.a.srt.bcnt[i] = 0u;
        if (tid == 0) sh.a.srt.flag = 0u;
        __syncthreads();
        const u32 LOB = __float_as_uint(PIVOT_S);
        for (int q = tid; q < m; q += NT) {
            u32 sb = (u32)(sh.k.keys[q] >> 32);
            u32 bi = (sb - LOB - 1u) >> 9;
            if (bi > (u32)(NB - 1)) bi = (u32)(NB - 1);
            atomicAdd(&sh.a.srt.bcnt[(u32)(NB - 1) - bi], 1u);   // bucket asc = score desc
        }
        __syncthreads();
        // exclusive scan over NB bins: 6 bins/thread (192*6=1152 >= 1024)
        u32 c[6];
        u32 s = 0;
        const int bb0 = tid * 6;
        #pragma unroll
        for (int i = 0; i < 6; ++i) {
            int idx = bb0 + i;
            c[i] = (idx < NB) ? sh.a.srt.bcnt[idx] : 0u;
            s += c[i];
        }
        u32 inc = s;
        #pragma unroll
        for (int o = 1; o < 64; o <<= 1) {
            u32 t = __shfl_up(inc, o, 64);
            if (lane >= o) inc += t;
        }
        if (lane == 63) sh.wsum[wv] = inc;
        __syncthreads();
        u32 wpre = 0;
        #pragma unroll
        for (int w = 0; w < 3; ++w) wpre += (w < wv) ? sh.wsum[w] : 0u;
        u32 run = wpre + inc - s;
        #pragma unroll
        for (int i = 0; i < 6; ++i) {
            int idx = bb0 + i;
            if (idx < NB) sh.a.srt.bcnt[idx] = run;
            run += c[i];
        }
        __syncthreads();
        // scatter (bins become end-cursors)
        for (int q = tid; q < m; q += NT) {
            u64 k = sh.k.keys[q];
            u32 sb = (u32)(k >> 32);
            u32 bi = (sb - LOB - 1u) >> 9;
            if (bi > (u32)(NB - 1)) bi = (u32)(NB - 1);
            u32 slot = atomicAdd(&sh.a.srt.bcnt[(u32)(NB - 1) - bi], 1u);
            sh.b.keys2[slot] = k;
        }
        __syncthreads();
        // per-bucket insertion sort desc (full 64-bit keys -> deterministic)
        for (int bb = tid; bb < NB; bb += NT) {
            u32 e = sh.a.srt.bcnt[bb];
            u32 st = bb ? sh.a.srt.bcnt[bb - 1] : 0u;
            if ((int)(e - st) > 32) { sh.a.srt.flag = 1u; continue; }
            for (u32 i = st + 1; i < e; ++i) {
                u64 x = sh.b.keys2[i];
                int j = (int)i - 1;
                while (j >= (int)st && sh.b.keys2[j] < x) {
                    sh.b.keys2[j + 1] = sh.b.keys2[j];
                    --j;
                }
                sh.b.keys2[j + 1] = x;
            }
        }
        __syncthreads();
        u32 fl = sh.a.srt.flag;
        if (!fl) {
            in_k2 = true;
        } else {
            // ~impossible exact fallback: zero-fill tail then full bitonic
            for (int q = tid; q < CAP; q += NT)
                if (q >= m) sh.k.keys[q] = 0ull;
            bitonic_desc(sh.k.keys, tid);
        }
    } else {
        bitonic_desc(sh.k.keys, tid);
    }

    // ---- Phase 3: decode candidate boxes (reference op order). Rows tid and
    // r2; BOTH keys read before the sync that allows box4 (union with keys2)
    // to be overwritten. Rows in [nk, TOP_K) are inf-padded (inter=0 -> never
    // suppress) so phase 4 can run fixed-trip chunk loops.
    {
        u64 k1 = 0ull, k2 = 0ull;
        if (tid < nk) k1 = in_k2 ? sh.b.keys2[tid] : sh.k.keys[tid];
        if (r2 < nk)  k2 = in_k2 ? sh.b.keys2[r2]  : sh.k.keys[r2];
        float4 lc1, pr1, lc2, pr2;
        if (tid < nk) {
            int p = (int)(~(u32)k1);
            lc1 = *(const float4*)(loc_data + ((size_t)img * NUM_PRIORS + p) * 4);
            pr1 = *(const float4*)(prior_data + (size_t)p * 4);
        }
        if (r2 < nk) {
            int p = (int)(~(u32)k2);
            lc2 = *(const float4*)(loc_data + ((size_t)img * NUM_PRIORS + p) * 4);
            pr2 = *(const float4*)(prior_data + (size_t)p * 4);
        }
        __syncthreads();   // keys2 fully consumed before box4 overwrites it
        const float INF = __int_as_float(0x7f800000);
        if (tid < TOP_K) {
            if (tid < nk) {
                float sc = __uint_as_float((u32)(k1 >> 32));
                float cx = pr1.x + (lc1.x * 0.1f) * pr1.z;
                float cy = pr1.y + (lc1.y * 0.1f) * pr1.w;
                float w  = pr1.z * exp_ref(lc1.z * 0.2f);
                float h  = pr1.w * exp_ref(lc1.w * 0.2f);
                float x1 = cx - 0.5f * w;
                float y1 = cy - 0.5f * h;
                float x2 = x1 + w;
                float y2 = y1 + h;
                sh.b.bx.box4[tid] = make_float4(x1, y1, x2, y2);
                sh.b.bx.area[tid] = fmaxf(x2 - x1, 0.0f) * fmaxf(y2 - y1, 0.0f);
                sh.b.bx.score[tid] = sc;
            } else {
                sh.b.bx.box4[tid] = make_float4(INF, INF, INF, INF);
                sh.b.bx.area[tid] = 0.0f;
                sh.b.bx.score[tid] = 0.0f;
            }
        }
        if (r2 < TOP_K) {
            if (r2 < nk) {
                float sc = __uint_as_float((u32)(k2 >> 32));
                float cx = pr2.x + (lc2.x * 0.1f) * pr2.z;
                float cy = pr2.y + (lc2.y * 0.1f) * pr2.w;
                float w  = pr2.z * exp_ref(lc2.z * 0.2f);
                float h  = pr2.w * exp_ref(lc2.w * 0.2f);
                float x1 = cx - 0.5f * w;
                float y1 = cy - 0.5f * h;
                float x2 = x1 + w;
                float y2 = y1 + h;
                sh.b.bx.box4[r2] = make_float4(x1, y1, x2, y2);
                sh.b.bx.area[r2] = fmaxf(x2 - x1, 0.0f) * fmaxf(y2 - y1, 0.0f);
                sh.b.bx.score[r2] = sc;
            } else {
                sh.b.bx.box4[r2] = make_float4(INF, INF, INF, INF);
                sh.b.bx.area[r2] = 0.0f;
                sh.b.bx.score[r2] = 0.0f;
            }
        }
    }
    __syncthreads();

    // ---- Phase 4: row-per-thread suppression masks (rows tid and r2),
    // chunk-specialized (CJ = wv is wave-uniform; r2 rows always chunk 3).
    {
        u64 mm1[4] = {0ull, 0ull, 0ull, 0ull};
        u64 mm2[4] = {0ull, 0ull, 0ull, 0ull};
        if (tid < nk) {
            if (wv == 0)      row_masks_t<0>(sh, tid, mm1);
            else if (wv == 1) row_masks_t<1>(sh, tid, mm1);
            else              row_masks_t<2>(sh, tid, mm1);
        }
        if (r2 < nk) row_masks_t<3>(sh, r2, mm2);
        if (tid < TOP_K) {
            sh.a.sup[tid][0] = mm1[0]; sh.a.sup[tid][1] = mm1[1];
            sh.a.sup[tid][2] = mm1[2]; sh.a.sup[tid][3] = mm1[3];
        }
        if (r2 < TOP_K) {
            sh.a.sup[r2][0] = mm2[0]; sh.a.sup[r2][1] = mm2[1];
            sh.a.sup[r2][2] = mm2[2]; sh.a.sup[r2][3] = mm2[3];
        }
    }
    __syncthreads();

    // ---- Phase 5: greedy resolve on wave 0 (64-bit chunks, shfl broadcast)
    if (wv == 0) {
        u64 kws[4];
        #pragma unroll
        for (int w = 0; w < 4; ++w) {
            int rem = nk - (w << 6);
            kws[w] = rem >= 64 ? ~0ull : (rem <= 0 ? 0ull : ((1ull << rem) - 1ull));
        }
        for (int c = 0; c < 4; ++c) {
            int row = (c << 6) + lane;
            u64 myrow = (row < TOP_K) ? sh.a.sup[row][c] : 0ull;
            u64 kw = kws[c];
            u64 nz = __ballot(myrow != 0ull);
            u64 t = kw & nz;
            while (t) {
                int j = __ffsll(t) - 1;
                u64 rj = __shfl(myrow, j, 64);
                kw &= ~rj;
                t &= ~(1ull << j);
                t &= kw;
            }
            kws[c] = kw;
            for (int w2 = c + 1; w2 < 4; ++w2) {
                u64 contrib = (row < TOP_K && ((kw >> lane) & 1ull)) ? sh.a.sup[row][w2] : 0ull;
                #pragma unroll
                for (int off = 32; off > 0; off >>= 1) contrib |= __shfl_xor(contrib, off, 64);
                kws[w2] &= ~contrib;
            }
        }
        if (lane == 0) {
            sh.keep[0] = kws[0]; sh.keep[1] = kws[1];
            sh.keep[2] = kws[2]; sh.keep[3] = kws[3];
        }
    }
    __syncthreads();

    // ---- Phase 6: stable compaction into LDS staging, then coalesced store.
    {
        float* os = (float*)sh.k.outstage4;
        for (int i = tid; i < (TOP_K * 5) / 2; i += NT) ((u64*)os)[i] = 0ull;
        __syncthreads();
        for (int row = tid; row < nk; row += NT) {
            int w = row >> 6, rr = row & 63;
            u64 kwv = sh.keep[w];
            if ((kwv >> rr) & 1ull) {
                int pos = __popcll(kwv & ((1ull << rr) - 1ull));
                for (int q = 0; q < w; ++q) pos += __popcll(sh.keep[q]);
                float4 bx = sh.b.bx.box4[row];
                os[pos * 5 + 0] = sh.b.bx.score[row];
                os[pos * 5 + 1] = bx.x;
                os[pos * 5 + 2] = bx.y;
                os[pos * 5 + 3] = bx.z;
                os[pos * 5 + 4] = bx.w;
            }
        }
        __syncthreads();
        float4* oslice = (float4*)(out + (((size_t)img * NUM_CLASSES + cl) * TOP_K) * 5);
        for (int i = tid; i < 250; i += NT) oslice[i] = sh.k.outstage4[i];
        if (r == 0) {  // this block also zeroes its image's class-0 (background) slice
            float4* bg = (float4*)(out + (((size_t)img * NUM_CLASSES) * TOP_K) * 5);
            for (int i = tid; i < 250; i += NT) bg[i] = make_float4(0.f, 0.f, 0.f, 0.f);
        }
    }
}

extern "C" void kernel_launch(void* const* d_in, const int* in_sizes, int n_in,
                              void* d_out, int out_size, void* d_ws, size_t ws_size,
                              hipStream_t stream) {
    const float* loc   = (const float*)d_in[0];
    const float* conf  = (const float*)d_in[1];
    const float* prior = (const float*)d_in[2];
    float* out = (float*)d_out;

    // ws layout: [0, NTASK*4) counts | [65536, 65536 + NTASK*CAP*8) keys
    const size_t need = 65536 + (size_t)NTASK * CAP * 8;
    const int use_ws = (ws_size >= need) ? 1 : 0;   // constant per session -> deterministic

    u32* counts = (u32*)d_ws;
    u64* keys   = (u64*)((char*)d_ws + 65536);

    if (use_ws) {
        // counts must be zeroed inside the graph each call (R15 lesson: relying
        // on cross-call ws state broke the fast path -> 3.7x regression).
        hipMemsetAsync(d_ws, 0, NTASK * sizeof(u32), stream);
        filter_kernel<<<FILTER_BLOCKS, 256, 0, stream>>>((const float4*)conf, counts, keys);
    }
    nms_kernel<<<NTASK, NT, 0, stream>>>(loc, conf, prior,
                                         use_ws ? counts : nullptr,
                                         use_ws ? keys : nullptr,
                                         out, use_ws);
}